// Round 4
// baseline (1226.329 us; speedup 1.0000x reference)
//
#include <hip/hip_runtime.h>
#include <hip/hip_bf16.h>

// Fused Linear + CrossEntropy on MI355X.
// Round 6: register-pipelined fragments. Post-mortem R0-R5: all schedules hit
// MfmaUtil ~45% because per-tile time == LDS-read-cycles + MFMA-cycles SUMMED
// (2736 cyc measured vs 1536+1242 model) -- the two pipes never overlap; every
// wave does [read burst][MFMA burst] in lockstep. Fix: operands for tile kt
// are read during tile kt-1's MFMA stream. Body kt: MFMA from registers, and
// the 12 ds_reads for tile kt+1 are interleaved INTO the MFMA stream, pinned
// by WAR hazards (a[mr] reloaded into the reg its own MFMAs just consumed).
// 4-wave blocks, wave tile 128x64 (fewer reads/MFMA), 2 blocks/CU.

typedef __attribute__((ext_vector_type(8))) short short8;
typedef __attribute__((ext_vector_type(8))) unsigned short ushort8;
typedef __attribute__((ext_vector_type(4))) float f32x4;

#define BT_TOTAL 8192
#define HDIM     2048
#define VDIM     32000
#define IGNORE_INDEX (-100)

constexpr int BM = 256, BN = 128, BK = 32;
constexpr int NVT = VDIM / BN;      // 250 vocab tiles
constexpr int NMT = BT_TOTAL / BM;  // 32 token tiles
constexpr int NKT = HDIM / BK;      // 64 K-tiles

__device__ __forceinline__ unsigned short f2bf(float f) {
    unsigned u = __float_as_uint(f);
    u = (u + 0x7FFFu + ((u >> 16) & 1u)) >> 16;   // RNE
    return (unsigned short)u;
}

__global__ void cvt_kernel(const float* __restrict__ in, unsigned short* __restrict__ out) {
    size_t i = ((size_t)blockIdx.x * blockDim.x + threadIdx.x) * 8;
    float4 a = *reinterpret_cast<const float4*>(in + i);
    float4 b = *reinterpret_cast<const float4*>(in + i + 4);
    ushort8 r;
    r[0] = f2bf(a.x); r[1] = f2bf(a.y); r[2] = f2bf(a.z); r[3] = f2bf(a.w);
    r[4] = f2bf(b.x); r[5] = f2bf(b.y); r[6] = f2bf(b.z); r[7] = f2bf(b.w);
    *reinterpret_cast<ushort8*>(out + i) = r;
}

#define GLDS(gp, lp) __builtin_amdgcn_global_load_lds( \
    (const __attribute__((address_space(1))) void*)(gp), \
    (__attribute__((address_space(3))) void*)(lp), 16, 0, 0)

__global__ __launch_bounds__(256, 2)
void flce_gemm(const unsigned short* __restrict__ xb,
               const unsigned short* __restrict__ wb,
               const int* __restrict__ labels,
               float* __restrict__ pmax, float* __restrict__ psum,
               float* __restrict__ tgt) {
    // LDS (53248 B): A dbuf 2x16KB @0 (256 rows x 32k), B dbuf 2x8KB @32768
    // (128 rows x 32k), scomb 4KB @49152.
    // Swizzled region layout (proven 0-conflict): row r, chunk c (8 bf16=16B)
    // at byte (r>>1)*128 + (r&1)*64 + ((c ^ ((r>>1)&3))<<4).
    __shared__ __align__(16) char smem[53248];

    const int t    = threadIdx.x;           // 0..255
    const int lane = t & 63;
    const int wid  = t >> 6;                // 4 waves
    const int li   = lane & 15;
    const int lg   = lane >> 4;             // k-chunk 0..3 within 32-k tile
    const int wm   = wid >> 1;              // 2 wave-rows (128 rows each)
    const int wn   = wid & 1;               // 2 wave-cols (64 cols each)

    // XCD-bijective supertiled mapping: 8000 blocks, 1000/XCD.
    int bid = blockIdx.x;
    int xcd = bid & 7;
    int idx = bid >> 3;                     // 0..999
    int p   = idx / 500;
    int r_  = idx % 500;
    int vt  = r_ >> 1;
    int mt  = xcd * 4 + p * 2 + (r_ & 1);
    const int row0 = mt * BM;
    const int col0 = vt * BN;

    // ---- staging lane constants (inverse-swizzled global source, linear LDS dest)
    // 256 threads x 16B = 4KB per issue = 64 rows. Thread t -> linear byte t*16:
    // pr=t>>3 (pair-row), rlow=(t>>2)&1, slot=t&3 -> row=2*pr+rlow, chunk=slot^(pr&3).
    const int rowLane  = 2 * (t >> 3) + ((t >> 2) & 1);     // 0..63
    const int srcChunk = (t & 3) ^ ((t >> 3) & 3);
    const unsigned short* aG = xb + (size_t)(row0 + rowLane) * HDIM + srcChunk * 8;
    const unsigned short* bG = wb + (size_t)(col0 + rowLane) * HDIM + srcChunk * 8;
    char* ldsA = smem;
    char* ldsB = smem + 32768;

    // ---- fragment-read lane constant
    const int laneFragOff = (li >> 1) * 128 + (li & 1) * 64
                          + ((lg ^ ((li >> 1) & 3)) << 4);

    f32x4 acc[8][4] = {};   // [mr][nr]: rows wm*128+mr*16+lg*4+j, cols wn*64+nr*16+li

    auto stageA = [&](int buf, int tile) {   // 256 rows = 4 issues/wave
        char* d = ldsA + buf * 16384 + wid * 1024;
        const unsigned short* s = aG + tile * 32;
        GLDS(s,                      d);
        GLDS(s + (size_t) 64 * HDIM, d + 4096);
        GLDS(s + (size_t)128 * HDIM, d + 8192);
        GLDS(s + (size_t)192 * HDIM, d + 12288);
    };
    auto stageB = [&](int buf, int tile) {   // 128 rows = 2 issues/wave
        char* d = ldsB + buf * 8192 + wid * 1024;
        const unsigned short* s = bG + tile * 32;
        GLDS(s,                      d);
        GLDS(s + (size_t) 64 * HDIM, d + 4096);
    };

    short8 a[8], bE[4], bO[4];

    // ---- prologue: stage tiles 0,1; read tile-0 fragments into registers
    stageA(0, 0); stageB(0, 0);
    stageA(1, 1); stageB(1, 1);
    asm volatile("s_waitcnt vmcnt(6)" ::: "memory");   // own tile-0 stages done
    __builtin_amdgcn_s_barrier();
    {
        const char* A0 = ldsA + wm * 8192;
        const char* B0 = ldsB + wn * 4096;
        #pragma unroll
        for (int i = 0; i < 8; ++i) a[i] = *(const short8*)(A0 + i * 1024 + laneFragOff);
        #pragma unroll
        for (int i = 0; i < 4; ++i) bE[i] = *(const short8*)(B0 + i * 1024 + laneFragOff);
    }

    // Body kt: MFMA with in-reg operands (tile kt); interleave ds_reads of tile
    // kt+1 into the MFMA stream (WAR-pinned); stage tile kt+2 into buf[kt&1].
    // Entry: lgkmcnt(0) = own reads from last body landed (also releases this
    // wave's read of the buffer others are about to overwrite); vmcnt(0) = own
    // stages for tile kt+1 (issued one body ago) landed; barrier = converge.
#define BODY(KT, BU, BL) do {                                                  \
    asm volatile("s_waitcnt lgkmcnt(0)" ::: "memory");                         \
    asm volatile("s_waitcnt vmcnt(0)" ::: "memory");                           \
    __builtin_amdgcn_s_barrier();                                              \
    {                                                                          \
        const int kt2_ = ((KT) + 2 < NKT) ? (KT) + 2 : (KT);                   \
        stageA((KT) & 1, kt2_); stageB((KT) & 1, kt2_);                        \
    }                                                                          \
    {                                                                          \
        const char* An_ = ldsA + (((KT) + 1) & 1) * 16384 + wm * 8192;         \
        const char* Bn_ = ldsB + (((KT) + 1) & 1) * 8192  + wn * 4096;         \
        _Pragma("unroll")                                                      \
        for (int mr = 0; mr < 8; ++mr) {                                       \
            _Pragma("unroll")                                                  \
            for (int nr = 0; nr < 4; ++nr)                                     \
                acc[mr][nr] = __builtin_amdgcn_mfma_f32_16x16x32_bf16(         \
                    a[mr], BU[nr], acc[mr][nr], 0, 0, 0);                      \
            a[mr] = *(const short8*)(An_ + mr * 1024 + laneFragOff);           \
            if (mr >= 4)                                                       \
                BL[mr - 4] = *(const short8*)(Bn_ + (mr - 4) * 1024 + laneFragOff); \
        }                                                                      \
    }                                                                          \
} while (0)

    for (int kt = 0; kt < NKT; kt += 2) {
        BODY(kt,     bE, bO);
        BODY(kt + 1, bO, bE);
    }
#undef BODY

    // ---- fused online-softmax epilogue over this 256x128 logits tile ----
    float* scombM = (float*)(smem + 49152);           // [2][256]
    float* scombS = scombM + 512;                     // [2][256]
    __syncthreads();   // drains dangling prefetches + converges before scomb use

    #pragma unroll
    for (int mr = 0; mr < 8; ++mr) {
        #pragma unroll
        for (int j = 0; j < 4; ++j) {
            float v = fmaxf(fmaxf(acc[mr][0][j], acc[mr][1][j]),
                            fmaxf(acc[mr][2][j], acc[mr][3][j]));
            v = fmaxf(v, __shfl_xor(v, 1));
            v = fmaxf(v, __shfl_xor(v, 2));
            v = fmaxf(v, __shfl_xor(v, 4));
            v = fmaxf(v, __shfl_xor(v, 8));
            float s = __expf(acc[mr][0][j] - v) + __expf(acc[mr][1][j] - v)
                    + __expf(acc[mr][2][j] - v) + __expf(acc[mr][3][j] - v);
            s += __shfl_xor(s, 1);
            s += __shfl_xor(s, 2);
            s += __shfl_xor(s, 4);
            s += __shfl_xor(s, 8);
            int row = wm * 128 + mr * 16 + lg * 4 + j;
            if (li == 0) {
                scombM[wn * 256 + row] = v;
                scombS[wn * 256 + row] = s;
            }
            // target-logit extraction
            int token = row0 + row;
            int lc = labels[token] - col0 - wn * 64;
            if (lc >= 0 && lc < 64 && (lc & 15) == li) {
                int nr = lc >> 4;
                float val = (nr == 0) ? acc[mr][0][j] : (nr == 1) ? acc[mr][1][j]
                          : (nr == 2) ? acc[mr][2][j] : acc[mr][3][j];
                tgt[token] = val;
            }
        }
    }
    __syncthreads();
    if (t < 256) {
        float m = scombM[t], s = scombS[t];
        float m2 = scombM[256 + t], s2 = scombS[256 + t];
        float mm = fmaxf(m, m2);
        s = s * __expf(m - mm) + s2 * __expf(m2 - mm);
        m = mm;
        size_t o = (size_t)vt * BT_TOTAL + row0 + t;
        pmax[o] = m;
        psum[o] = s;
    }
}

__global__ void flce_reduce(const float* __restrict__ pmax, const float* __restrict__ psum,
                            const float* __restrict__ tgt, const int* __restrict__ labels,
                            float* __restrict__ accum) {
    int token = blockIdx.x * 256 + threadIdx.x;
    float m = -INFINITY, s = 0.f;
    for (int v = 0; v < NVT; ++v) {
        float pm = pmax[(size_t)v * BT_TOTAL + token];
        float ps = psum[(size_t)v * BT_TOTAL + token];
        float nm = fmaxf(m, pm);
        s = s * __expf(m - nm) + ps * __expf(pm - nm);
        m = nm;
    }
    float nll = 0.f, cnt = 0.f;
    int lab = labels[token];
    if (lab != IGNORE_INDEX) {
        nll = (m + __logf(s)) - tgt[token];
        cnt = 1.f;
    }
    #pragma unroll
    for (int d = 32; d > 0; d >>= 1) {
        nll += __shfl_down(nll, d);
        cnt += __shfl_down(cnt, d);
    }
    __shared__ float sn[4], sc[4];
    int w = threadIdx.x >> 6;
    if ((threadIdx.x & 63) == 0) { sn[w] = nll; sc[w] = cnt; }
    __syncthreads();
    if (threadIdx.x == 0) {
        atomicAdd(&accum[0], sn[0] + sn[1] + sn[2] + sn[3]);
        atomicAdd(&accum[1], sc[0] + sc[1] + sc[2] + sc[3]);
    }
}

__global__ void flce_final(const float* __restrict__ accum, float* __restrict__ out) {
    if (threadIdx.x == 0) out[0] = accum[0] / fmaxf(accum[1], 1.0f);
}

extern "C" void kernel_launch(void* const* d_in, const int* in_sizes, int n_in,
                              void* d_out, int out_size, void* d_ws, size_t ws_size,
                              hipStream_t stream) {
    const float* hs     = (const float*)d_in[0];   // [8192, 2048] fp32
    const int*   labels = (const int*)d_in[1];     // [8192]
    const float* wt     = (const float*)d_in[2];   // [32000, 2048] fp32

    char* ws = (char*)d_ws;
    unsigned short* xb    = (unsigned short*)(ws);                 // 33,554,432 B
    unsigned short* wb    = (unsigned short*)(ws + 33554432);      // 131,072,000 B
    float*          pmax  = (float*)(ws + 164626432);              // 8,192,000 B
    float*          psum  = (float*)(ws + 172818432);              // 8,192,000 B
    float*          tgt   = (float*)(ws + 181010432);              // 32,768 B
    float*          accum = (float*)(ws + 181043200);              // 8 B

    hipMemsetAsync(accum, 0, 8, stream);
    cvt_kernel<<<16777216 / 2048, 256, 0, stream>>>(hs, xb);
    cvt_kernel<<<65536000 / 2048, 256, 0, stream>>>(wt, wb);
    flce_gemm<<<NMT * NVT, 256, 0, stream>>>(xb, wb, labels, pmax, psum, tgt);
    flce_reduce<<<BT_TOTAL / 256, 256, 0, stream>>>(pmax, psum, tgt, labels, accum);
    flce_final<<<1, 64, 0, stream>>>(accum, (float*)d_out);
}